// Round 6
// baseline (6783.630 us; speedup 1.0000x reference)
//
#include <hip/hip_runtime.h>
#include <hip/hip_bf16.h>

#define LL 4
#define NN 50000
#define EE 625000
#define DD 128

typedef __hip_bfloat16 bf16;
typedef unsigned char u8;

__device__ __forceinline__ float b2f(bf16 v) { return __bfloat162float(v); }

// ---- manual OCP fp8 e4m3fn codec ----
__device__ __forceinline__ u8 f2e4m3(float x) {
    if (x != x) return 0x7f;
    u8 s = (x < 0.0f) ? 0x80 : 0x00;
    float a = fabsf(x);
    if (a >= 448.0f) return s | 0x7e;
    if (a < 0.0009765625f) return s;
    int e;
    float m = frexpf(a, &e);
    int E = e - 1;
    if (E < -6) {
        int f = (int)rintf(a * 512.0f);
        if (f >= 8) return s | 0x08;
        return s | (u8)f;
    }
    int f = (int)rintf(m * 16.0f);
    if (f == 16) { E++; f = 8; }
    if (E > 8) return s | 0x7e;
    return s | (u8)(((E + 7) << 3) | (f & 7));
}
__device__ __forceinline__ float e4m32f(u8 v) {
    int ex = (v >> 3) & 0xF, man = v & 7;
    float a;
    if (ex == 0) a = (float)man * 0.001953125f;
    else a = ldexpf(1.0f + (float)man * 0.125f, ex - 7);
    return (v & 0x80) ? -a : a;
}

// ---- typed load/store for workspace tensors: t=0 fp32, 1 bf16, 2 fp8 ----
__device__ __forceinline__ float loadT(const void* p, size_t i, int t) {
    if (t == 0) return ((const float*)p)[i];
    if (t == 1) return b2f(((const bf16*)p)[i]);
    return e4m32f(((const u8*)p)[i]);
}
__device__ __forceinline__ void storeT(void* p, size_t i, int t, float v) {
    if (t == 0) ((float*)p)[i] = v;
    else if (t == 1) ((bf16*)p)[i] = __float2bfloat16(v);
    else ((u8*)p)[i] = f2e4m3(v);
}

__device__ __forceinline__ float gelu_tanh(float v) {
    const float c = 0.7978845608028654f;
    float u = c * (v + 0.044715f * v * v * v);
    return 0.5f * v * (1.0f + tanhf(u));
}
__device__ __forceinline__ float sigmoidf_(float x) {
    return 1.0f / (1.0f + __expf(-x));
}

// ---------------- utility ----------------
__global__ __launch_bounds__(256) void k_zero(int* __restrict__ p, int n) {
    int i = blockIdx.x * 256 + threadIdx.x;
    if (i < n) p[i] = 0;
}

// ---------------- CSR build ----------------
__global__ __launch_bounds__(256) void k_count(const int* __restrict__ edst, int* __restrict__ deg) {
    int e = blockIdx.x * 256 + threadIdx.x;
    if (e < EE) atomicAdd(&deg[edst[e]], 1);
}

__global__ __launch_bounds__(1024) void k_scan(const int* __restrict__ deg, int* __restrict__ row_ptr,
                                               int* __restrict__ cursor) {
    __shared__ int temp[1024];
    __shared__ int carry;
    int tid = threadIdx.x;
    if (tid == 0) carry = 0;
    __syncthreads();
    for (int base = 0; base < NN; base += 1024) {
        int i = base + tid;
        int v = (i < NN) ? deg[i] : 0;
        temp[tid] = v;
        __syncthreads();
        for (int off = 1; off < 1024; off <<= 1) {
            int t = (tid >= off) ? temp[tid - off] : 0;
            __syncthreads();
            temp[tid] += t;
            __syncthreads();
        }
        int excl = temp[tid] - v + carry;
        if (i < NN) { row_ptr[i] = excl; cursor[i] = excl; }
        __syncthreads();
        if (tid == 1023) carry += temp[1023];
        __syncthreads();
    }
    if (tid == 0) row_ptr[NN] = carry;
}

__global__ __launch_bounds__(256) void k_scatter(const int* __restrict__ edst, int* __restrict__ cursor,
                                                 int* __restrict__ perm) {
    int e = blockIdx.x * 256 + threadIdx.x;
    if (e < EE) {
        int p = atomicAdd(&cursor[edst[e]], 1);
        perm[p] = e;
    }
}

// ---------------- K1: node GEMM, 2 matrices per call ----------------
__global__ __launch_bounds__(256) void k_node_gemm2(
    const void* __restrict__ x, int xt,
    const float* __restrict__ WX, const float* __restrict__ WY,
    const float* __restrict__ bX, const float* __restrict__ bY,
    void* __restrict__ OX, void* __restrict__ OY, int nt) {
    __shared__ float smem[12352];          // w_lds[64][128] + x_lds[64][65]
    float* w_lds = smem;
    float* x_lds = smem + 8192;
    int tid = threadIdx.x, wid = tid >> 6, lane = tid & 63;
    int base = blockIdx.x * 64;
    for (int m = 0; m < 2; m++) {
        const float* W = (m == 0) ? WX : WY;
        const float* bb = (m == 0) ? bX : bY;
        void* O = (m == 0) ? OX : OY;
        float acc[32];
#pragma unroll
        for (int jj = 0; jj < 32; jj++) acc[jj] = bb[wid * 32 + jj];
        for (int h = 0; h < 2; h++) {
            __syncthreads();
            for (int idx = tid; idx < 8192; idx += 256)
                w_lds[idx] = W[(h * 64 + (idx >> 7)) * 128 + (idx & 127)];
            for (int idx = tid; idx < 4096; idx += 256) {
                int r = idx >> 6, kl = idx & 63;
                int n = base + r;
                float xv = 0.0f;
                if (n < NN) xv = loadT(x, (size_t)n * 128 + h * 64 + kl, xt);
                x_lds[r * 65 + kl] = xv;
            }
            __syncthreads();
            const float4* w4 = (const float4*)w_lds;
            for (int kl = 0; kl < 64; kl++) {
                float xk = x_lds[lane * 65 + kl];
#pragma unroll
                for (int j4 = 0; j4 < 8; j4++) {
                    float4 wv = w4[kl * 32 + wid * 8 + j4];
                    acc[j4 * 4 + 0] += xk * wv.x;
                    acc[j4 * 4 + 1] += xk * wv.y;
                    acc[j4 * 4 + 2] += xk * wv.z;
                    acc[j4 * 4 + 3] += xk * wv.w;
                }
            }
        }
        __syncthreads();
#pragma unroll
        for (int jj = 0; jj < 32; jj++) smem[lane * 129 + wid * 32 + jj] = acc[jj];
        __syncthreads();
        for (int idx = tid; idx < 8192; idx += 256) {
            int r = idx >> 7, k = idx & 127;
            if (base + r < NN) storeT(O, (size_t)(base + r) * 128 + k, nt, smem[r * 129 + k]);
        }
    }
}

// ---------------- K2: fused edge pass ----------------
__global__ __launch_bounds__(256) void k_edge(
    int layer, int write_e, int accum_stats,
    void* __restrict__ e, int et, void* __restrict__ e_ij, int jt,
    const int* __restrict__ esrc, const int* __restrict__ edst,
    const int* __restrict__ eattr, const float* __restrict__ bond,
    const float* __restrict__ WC, const float* __restrict__ bC,
    const void* __restrict__ Dx, const void* __restrict__ Ex, int nt,
    const float* __restrict__ stats_prev,
    const float* __restrict__ gE, const float* __restrict__ bEb,
    float* __restrict__ stats_out) {
    __shared__ float smem[12352];
    float* w_lds = smem;
    float* e_lds = smem + 8192;
    int tid = threadIdx.x, wid = tid >> 6, lane = tid & 63;
    int base = blockIdx.x * 64;
    const float invE = 1.0f / (float)EE;

    float acc[32];
#pragma unroll
    for (int jj = 0; jj < 32; jj++) acc[jj] = bC[wid * 32 + jj];

    for (int h = 0; h < 2; h++) {
        __syncthreads();
        for (int idx = tid; idx < 8192; idx += 256)
            w_lds[idx] = WC[(h * 64 + (idx >> 7)) * 128 + (idx & 127)];
        for (int idx = tid; idx < 4096; idx += 256) {
            int r = idx >> 6, kl = idx & 63;
            int edge = base + r;
            int k = h * 64 + kl;
            float ev = 0.0f;
            if (edge < EE) {
                if (layer == 0) {
                    int a0 = eattr[edge * 3 + 0];
                    int a1 = eattr[edge * 3 + 1];
                    int a2 = eattr[edge * 3 + 2];
                    ev = bond[a0 * 128 + k] + bond[(37 + a1) * 128 + k] + bond[(74 + a2) * 128 + k];
                } else {
                    float ep = loadT(e, (size_t)edge * 128 + k, et);
                    float hij = loadT(e_ij, (size_t)edge * 128 + k, jt);
                    float m = stats_prev[k] * invE;
                    float var = stats_prev[128 + k] * invE - m * m;
                    float y = gE[k] * (hij - m) * rsqrtf(var + 1e-5f) + bEb[k];
                    ev = ep + gelu_tanh(y);
                }
                if (write_e) storeT(e, (size_t)edge * 128 + k, et, ev);
            }
            e_lds[r * 65 + kl] = ev;
        }
        __syncthreads();
        const float4* w4 = (const float4*)w_lds;
        for (int kl = 0; kl < 64; kl++) {
            float ek = e_lds[lane * 65 + kl];
#pragma unroll
            for (int j4 = 0; j4 < 8; j4++) {
                float4 wv = w4[kl * 32 + wid * 8 + j4];
                acc[j4 * 4 + 0] += ek * wv.x;
                acc[j4 * 4 + 1] += ek * wv.y;
                acc[j4 * 4 + 2] += ek * wv.z;
                acc[j4 * 4 + 3] += ek * wv.w;
            }
        }
    }
    __syncthreads();
    int edge = base + lane;
    bool valid = (edge < EE);
    int dn = valid ? edst[edge] : 0;
    int sn = valid ? esrc[edge] : 0;
#pragma unroll
    for (int jj = 0; jj < 32; jj++) {
        int j = wid * 32 + jj;
        float val = acc[jj] + loadT(Dx, (size_t)dn * 128 + j, nt) + loadT(Ex, (size_t)sn * 128 + j, nt);
        smem[lane * 129 + j] = valid ? val : 0.0f;
    }
    __syncthreads();
    for (int idx = tid; idx < 8192; idx += 256) {
        int r = idx >> 7, k = idx & 127;
        if (base + r < EE)
            storeT(e_ij, (size_t)(base + r) * 128 + k, jt, smem[r * 129 + k]);
    }
    if (accum_stats) {
        int c = tid & 127, hh = tid >> 7;
        float s = 0.0f, q = 0.0f;
        for (int r = 0; r < 64; r++) {
            float v = smem[r * 129 + c];
            s += v;
            q += v * v;
        }
        if (hh == 0) atomicAdd(&stats_out[c], s);
        else         atomicAdd(&stats_out[128 + c], q);
    }
}

// ---------------- K3: CSR aggregation (wave per node) ----------------
// x_new aliases Ax (P0): thread n reads Ax[n] then writes x_new[n] (same
// element, same thread); Bx lives in P1 -> no cross-thread hazard.
__global__ __launch_bounds__(256) void k_aggr(
    const int* __restrict__ row_ptr, const int* __restrict__ perm,
    const int* __restrict__ esrc, const void* __restrict__ e_ij, int jt,
    const void* __restrict__ Bx, const void* __restrict__ Ax, int nt,
    void* __restrict__ x_new) {
    int tid = threadIdx.x, wid = tid >> 6, lane = tid & 63;
    int n = blockIdx.x * 4 + wid;
    if (n >= NN) return;
    int s0 = row_ptr[n], s1 = row_ptr[n + 1];
    float num0 = 0.0f, num1 = 0.0f, den0 = 0.0f, den1 = 0.0f;
    for (int i = s0; i < s1; i++) {
        int eid = perm[i];
        int src = esrc[eid];
        float g0 = sigmoidf_(loadT(e_ij, (size_t)eid * 128 + lane, jt));
        float g1 = sigmoidf_(loadT(e_ij, (size_t)eid * 128 + 64 + lane, jt));
        num0 += g0 * loadT(Bx, (size_t)src * 128 + lane, nt);
        num1 += g1 * loadT(Bx, (size_t)src * 128 + 64 + lane, nt);
        den0 += g0;
        den1 += g1;
    }
    float a0 = loadT(Ax, (size_t)n * 128 + lane, nt);
    float a1 = loadT(Ax, (size_t)n * 128 + 64 + lane, nt);
    storeT(x_new, (size_t)n * 128 + lane,      nt, a0 + num0 / (den0 + 1e-6f));
    storeT(x_new, (size_t)n * 128 + 64 + lane, nt, a1 + num1 / (den1 + 1e-6f));
}

// ---------------- K4: per-channel stats of x_new ----------------
__global__ __launch_bounds__(256) void k_xstats(const void* __restrict__ x_new, int nt,
                                                float* __restrict__ stats) {
    int tid = threadIdx.x;
    int c = tid & 127, hh = tid >> 7;
    float s = 0.0f, q = 0.0f;
    for (int r = blockIdx.x * 2 + hh; r < NN; r += (int)gridDim.x * 2) {
        float v = loadT(x_new, (size_t)r * 128 + c, nt);
        s += v;
        q += v * v;
    }
    atomicAdd(&stats[c], s);
    atomicAdd(&stats[128 + c], q);
}

// ---------------- K5: x update ----------------
__global__ __launch_bounds__(256) void k_xupd(
    const void* __restrict__ xin, int xt,
    const void* __restrict__ x_new, int nt,
    const float* __restrict__ stats, const float* __restrict__ g,
    const float* __restrict__ bb, void* __restrict__ xout, int ot) {
    int idx = blockIdx.x * 256 + threadIdx.x;
    if (idx >= NN * 128) return;
    int c = idx & 127;
    const float invN = 1.0f / (float)NN;
    float m = stats[c] * invN;
    float var = stats[128 + c] * invN - m * m;
    float y = g[c] * (loadT(x_new, idx, nt) - m) * rsqrtf(var + 1e-5f) + bb[c];
    float xi = loadT(xin, idx, xt);
    storeT(xout, idx, ot, xi + gelu_tanh(y));
}

extern "C" void kernel_launch(void* const* d_in, const int* in_sizes, int n_in,
                              void* d_out, int out_size, void* d_ws, size_t ws_size,
                              hipStream_t stream) {
    const float* X_n  = (const float*)d_in[0];
    const int*  eidx  = (const int*)d_in[2];
    const int*  eattr = (const int*)d_in[3];
    const float* bond = (const float*)d_in[4];
    const float* WA = (const float*)d_in[5];  const float* bA = (const float*)d_in[6];
    const float* WB = (const float*)d_in[7];  const float* bB = (const float*)d_in[8];
    const float* WC = (const float*)d_in[9];  const float* bC = (const float*)d_in[10];
    const float* WD = (const float*)d_in[11]; const float* bD = (const float*)d_in[12];
    const float* WE = (const float*)d_in[13]; const float* bE = (const float*)d_in[14];
    const float* bn_x_g = (const float*)d_in[15];
    const float* bn_x_b = (const float*)d_in[16];
    const float* bn_e_g = (const float*)d_in[17];
    const float* bn_e_b = (const float*)d_in[18];

    const int* esrc = eidx;
    const int* edst = eidx + EE;

    // ---- precision ladder: pick the highest-precision config that fits ----
    // fields: {e, e_ij, node-mats(P0/P1 + x_new alias), x_buf}; 0=fp32 1=bf16 2=fp8
    auto tsz = [](int t) -> size_t { return t == 0 ? 4 : (t == 1 ? 2 : 1); };
    int cfgs[7][4] = {
        {1, 1, 0, 0},   // ~400 MB
        {1, 1, 1, 0},   // ~374 MB
        {1, 2, 0, 0},   // ~320 MB
        {1, 2, 1, 0},   // ~294 MB
        {2, 2, 0, 0},   // ~240 MB
        {2, 2, 1, 0},   // ~214 MB
        {2, 2, 1, 1},   // ~202 MB
    };
    const size_t ND = (size_t)NN * DD, ED = (size_t)EE * DD;
    int chosen = -1;
    for (int c = 0; c < 7; c++) {
        size_t need = ED * (tsz(cfgs[c][0]) + tsz(cfgs[c][1]))
                    + ND * (2 * tsz(cfgs[c][2]) + tsz(cfgs[c][3]))
                    + 2048 * 4
                    + ((size_t)NN * 3 + 1 + EE) * 4
                    + 16 * 256;
        if (ws_size >= need) { chosen = c; break; }
    }
    if (chosen < 0) return;  // ws < ~202 MB: diagnostic (absmax == max|ref|)
    int et = cfgs[chosen][0], jt = cfgs[chosen][1], nt = cfgs[chosen][2], xt = cfgs[chosen][3];

    size_t off = 0;
    auto carve = [&](size_t bytes) -> void* {
        void* p = (char*)d_ws + off;
        off += (bytes + 255) & ~(size_t)255;
        return p;
    };
    float* e_stats = (float*)carve(1024 * 4);
    float* x_stats = (float*)carve(1024 * 4);
    int* deg     = (int*)carve((size_t)NN * 4);
    int* row_ptr = (int*)carve(((size_t)NN + 1) * 4);
    int* cursor  = (int*)carve((size_t)NN * 4);
    int* perm    = (int*)carve((size_t)EE * 4);
    void* x_buf  = carve(ND * tsz(xt));
    void* P0     = carve(ND * tsz(nt));     // Dx then Ax; x_new aliases P0
    void* P1     = carve(ND * tsz(nt));     // Ex then Bx
    void* e      = carve(ED * tsz(et));
    void* e_ij   = carve(ED * tsz(jt));
    void* x_new  = P0;

    k_zero<<<(NN + 255) / 256, 256, 0, stream>>>(deg, NN);
    k_zero<<<8, 256, 0, stream>>>((int*)e_stats, 2048);

    int egrid = (EE + 255) / 256;
    k_count<<<egrid, 256, 0, stream>>>(edst, deg);
    k_scan<<<1, 1024, 0, stream>>>(deg, row_ptr, cursor);
    k_scatter<<<egrid, 256, 0, stream>>>(edst, cursor, perm);

    const int ngemm_grid = (NN + 63) / 64;
    const int edge_grid  = (EE + 63) / 64;
    const int aggr_grid  = (NN + 3) / 4;
    const int upd_grid   = (NN * DD + 255) / 256;

    for (int l = 0; l < LL; l++) {
        const void* xin = (l == 0) ? (const void*)X_n : (const void*)x_buf;
        int xint = (l == 0) ? 0 : xt;

        // phase A: Dx -> P0, Ex -> P1
        k_node_gemm2<<<ngemm_grid, 256, 0, stream>>>(
            xin, xint,
            WD + (size_t)l * DD * DD, WE + (size_t)l * DD * DD,
            bD + l * DD, bE + l * DD, P0, P1, nt);

        int prev = (l > 0) ? (l - 1) : 0;
        k_edge<<<edge_grid, 256, 0, stream>>>(
            l, (l < 3) ? 1 : 0, (l < 3) ? 1 : 0,
            e, et, e_ij, jt, esrc, edst, eattr, bond,
            WC + (size_t)l * DD * DD, bC + l * DD,
            P0, P1, nt,
            e_stats + prev * 256, bn_e_g + prev * DD, bn_e_b + prev * DD,
            e_stats + l * 256);

        // phase B: Ax -> P0, Bx -> P1
        k_node_gemm2<<<ngemm_grid, 256, 0, stream>>>(
            xin, xint,
            WA + (size_t)l * DD * DD, WB + (size_t)l * DD * DD,
            bA + l * DD, bB + l * DD, P0, P1, nt);

        k_aggr<<<aggr_grid, 256, 0, stream>>>(row_ptr, perm, esrc, e_ij, jt, P1, P0, nt, x_new);
        k_xstats<<<256, 256, 0, stream>>>(x_new, nt, x_stats + l * 256);

        void* xo = (l == 3) ? d_out : x_buf;
        int ot = (l == 3) ? 0 : xt;
        k_xupd<<<upd_grid, 256, 0, stream>>>(xin, xint, x_new, nt, x_stats + l * 256,
                                             bn_x_g + l * DD, bn_x_b + l * DD, xo, ot);
    }
}

// Round 7
// 3835.443 us; speedup vs baseline: 1.7687x; 1.7687x over previous
//
#include <hip/hip_runtime.h>
#include <hip/hip_bf16.h>

#define LL 4
#define NN 50000
#define EE 625000
#define DD 128

#define PADA 136   // bf16 A-tile row pitch (elements)
#define PADO 132   // fp32 out-tile row pitch (elements)

typedef __hip_bfloat16 bf16;
typedef unsigned char u8;
typedef unsigned short ushort_t;
typedef __attribute__((ext_vector_type(8))) short s8v;   // 8 bf16 (4 VGPRs)
typedef __attribute__((ext_vector_type(4))) float f4v;   // 4 fp32 acc

__device__ __forceinline__ float b2f(bf16 v) { return __bfloat162float(v); }
__device__ __forceinline__ ushort_t f2b_bits(float v) {
    bf16 h = __float2bfloat16(v);
    return *reinterpret_cast<ushort_t*>(&h);
}
__device__ __forceinline__ float bits2f(ushort_t u) {
    bf16 h;
    *reinterpret_cast<ushort_t*>(&h) = u;
    return __bfloat162float(h);
}

// ---- manual OCP fp8 e4m3fn codec ----
__device__ __forceinline__ u8 f2e4m3(float x) {
    if (x != x) return 0x7f;
    u8 s = (x < 0.0f) ? 0x80 : 0x00;
    float a = fabsf(x);
    if (a >= 448.0f) return s | 0x7e;
    if (a < 0.0009765625f) return s;
    int e;
    float m = frexpf(a, &e);
    int E = e - 1;
    if (E < -6) {
        int f = (int)rintf(a * 512.0f);
        if (f >= 8) return s | 0x08;
        return s | (u8)f;
    }
    int f = (int)rintf(m * 16.0f);
    if (f == 16) { E++; f = 8; }
    if (E > 8) return s | 0x7e;
    return s | (u8)(((E + 7) << 3) | (f & 7));
}
__device__ __forceinline__ float e4m32f(u8 v) {
    int ex = (v >> 3) & 0xF, man = v & 7;
    float a;
    if (ex == 0) a = (float)man * 0.001953125f;
    else a = ldexpf(1.0f + (float)man * 0.125f, ex - 7);
    return (v & 0x80) ? -a : a;
}

// ---- typed scalar load/store: t=0 fp32, 1 bf16, 2 fp8 ----
__device__ __forceinline__ float loadT(const void* p, size_t i, int t) {
    if (t == 0) return ((const float*)p)[i];
    if (t == 1) return b2f(((const bf16*)p)[i]);
    return e4m32f(((const u8*)p)[i]);
}
__device__ __forceinline__ void storeT(void* p, size_t i, int t, float v) {
    if (t == 0) ((float*)p)[i] = v;
    else if (t == 1) ((bf16*)p)[i] = __float2bfloat16(v);
    else ((u8*)p)[i] = f2e4m3(v);
}

// ---- 8-wide vector load/store (i must be 8-aligned; buffers 16B aligned) ----
__device__ __forceinline__ void load8(const void* p, size_t i, int t, float* v) {
    if (t == 1) {
        uint4 u = *(const uint4*)((const ushort_t*)p + i);
        const ushort_t* us = (const ushort_t*)&u;
#pragma unroll
        for (int j = 0; j < 8; j++) v[j] = bits2f(us[j]);
    } else if (t == 2) {
        uint2 u = *(const uint2*)((const u8*)p + i);
        const u8* b = (const u8*)&u;
#pragma unroll
        for (int j = 0; j < 8; j++) v[j] = e4m32f(b[j]);
    } else {
        const float* f = (const float*)p + i;
#pragma unroll
        for (int j = 0; j < 8; j++) v[j] = f[j];
    }
}
__device__ __forceinline__ void store8(void* p, size_t i, int t, const float* v) {
    if (t == 1) {
        ushort_t tmp[8];
#pragma unroll
        for (int j = 0; j < 8; j++) tmp[j] = f2b_bits(v[j]);
        *(uint4*)((ushort_t*)p + i) = *(const uint4*)tmp;
    } else if (t == 2) {
        u8 tmp[8];
#pragma unroll
        for (int j = 0; j < 8; j++) tmp[j] = f2e4m3(v[j]);
        *(uint2*)((u8*)p + i) = *(const uint2*)tmp;
    } else {
        float* f = (float*)p + i;
#pragma unroll
        for (int j = 0; j < 8; j++) f[j] = v[j];
    }
}

__device__ __forceinline__ float gelu_tanh(float v) {
    const float c = 0.7978845608028654f;
    float u = c * (v + 0.044715f * v * v * v);
    return 0.5f * v * (1.0f + tanhf(u));
}
__device__ __forceinline__ float sigmoidf_(float x) {
    return 1.0f / (1.0f + __expf(-x));
}

// ---------------- utility ----------------
__global__ __launch_bounds__(256) void k_zero(int* __restrict__ p, int n) {
    int i = blockIdx.x * 256 + threadIdx.x;
    if (i < n) p[i] = 0;
}

// ---------------- CSR build ----------------
__global__ __launch_bounds__(256) void k_count(const int* __restrict__ edst, int* __restrict__ deg) {
    int e = blockIdx.x * 256 + threadIdx.x;
    if (e < EE) atomicAdd(&deg[edst[e]], 1);
}

__global__ __launch_bounds__(1024) void k_scan(const int* __restrict__ deg, int* __restrict__ row_ptr,
                                               int* __restrict__ cursor) {
    __shared__ int temp[1024];
    __shared__ int carry;
    int tid = threadIdx.x;
    if (tid == 0) carry = 0;
    __syncthreads();
    for (int base = 0; base < NN; base += 1024) {
        int i = base + tid;
        int v = (i < NN) ? deg[i] : 0;
        temp[tid] = v;
        __syncthreads();
        for (int off = 1; off < 1024; off <<= 1) {
            int t = (tid >= off) ? temp[tid - off] : 0;
            __syncthreads();
            temp[tid] += t;
            __syncthreads();
        }
        int excl = temp[tid] - v + carry;
        if (i < NN) { row_ptr[i] = excl; cursor[i] = excl; }
        __syncthreads();
        if (tid == 1023) carry += temp[1023];
        __syncthreads();
    }
    if (tid == 0) row_ptr[NN] = carry;
}

__global__ __launch_bounds__(256) void k_scatter(const int* __restrict__ edst, int* __restrict__ cursor,
                                                 int* __restrict__ perm) {
    int e = blockIdx.x * 256 + threadIdx.x;
    if (e < EE) {
        int p = atomicAdd(&cursor[edst[e]], 1);
        perm[p] = e;
    }
}

// ---------------- W prep: WC -> bf16 B-fragment order ----------------
// fragment (kc,n): lane l holds B[k=kc*32+(l>>4)*8+j][col=n*16+(l&15)], j=0..7
// WCf index: ((layer*32 + kc*8+n)*64 + l)*8 + j
__global__ __launch_bounds__(256) void k_wprep(const float* __restrict__ WC, ushort_t* __restrict__ WCf) {
    int tid = blockIdx.x * 256 + threadIdx.x;
    if (tid >= 4 * 32 * 64 * 8) return;
    int j = tid & 7;
    int l6 = (tid >> 3) & 63;
    int f = (tid >> 9) & 31;
    int layer = tid >> 14;
    int kc = f >> 3, n = f & 7;
    int k = kc * 32 + (l6 >> 4) * 8 + j;
    int col = n * 16 + (l6 & 15);
    WCf[tid] = f2b_bits(WC[(size_t)layer * 16384 + k * 128 + col]);
}

// ---------------- K1: node GEMM, 2 matrices per call ----------------
__global__ __launch_bounds__(256) void k_node_gemm2(
    const void* __restrict__ x, int xt,
    const float* __restrict__ WX, const float* __restrict__ WY,
    const float* __restrict__ bX, const float* __restrict__ bY,
    void* __restrict__ OX, void* __restrict__ OY, int nt) {
    __shared__ float smem[12352];          // w_lds[64][128] + x_lds[64][65]
    float* w_lds = smem;
    float* x_lds = smem + 8192;
    int tid = threadIdx.x, wid = tid >> 6, lane = tid & 63;
    int base = blockIdx.x * 64;
    for (int m = 0; m < 2; m++) {
        const float* W = (m == 0) ? WX : WY;
        const float* bb = (m == 0) ? bX : bY;
        void* O = (m == 0) ? OX : OY;
        float acc[32];
#pragma unroll
        for (int jj = 0; jj < 32; jj++) acc[jj] = bb[wid * 32 + jj];
        for (int h = 0; h < 2; h++) {
            __syncthreads();
            for (int idx = tid; idx < 8192; idx += 256)
                w_lds[idx] = W[(h * 64 + (idx >> 7)) * 128 + (idx & 127)];
            for (int idx = tid; idx < 4096; idx += 256) {
                int r = idx >> 6, kl = idx & 63;
                int n = base + r;
                float xv = 0.0f;
                if (n < NN) xv = loadT(x, (size_t)n * 128 + h * 64 + kl, xt);
                x_lds[r * 65 + kl] = xv;
            }
            __syncthreads();
            const float4* w4 = (const float4*)w_lds;
            for (int kl = 0; kl < 64; kl++) {
                float xk = x_lds[lane * 65 + kl];
#pragma unroll
                for (int j4 = 0; j4 < 8; j4++) {
                    float4 wv = w4[kl * 32 + wid * 8 + j4];
                    acc[j4 * 4 + 0] += xk * wv.x;
                    acc[j4 * 4 + 1] += xk * wv.y;
                    acc[j4 * 4 + 2] += xk * wv.z;
                    acc[j4 * 4 + 3] += xk * wv.w;
                }
            }
        }
        __syncthreads();
#pragma unroll
        for (int jj = 0; jj < 32; jj++) smem[lane * 129 + wid * 32 + jj] = acc[jj];
        __syncthreads();
        for (int idx = tid; idx < 8192; idx += 256) {
            int r = idx >> 7, k = idx & 127;
            if (base + r < NN) storeT(O, (size_t)(base + r) * 128 + k, nt, smem[r * 129 + k]);
        }
    }
}

// ---------------- K2: fused edge pass (MFMA) ----------------
// 64 edges/block, 4 waves. Stage e (apply prev-layer e-update, write back),
// Ce = e@WC via mfma_f32_16x16x32_bf16, add Dx[dst]+Ex[src]+bC, BN stats from
// fp32, coalesced e_ij store.
__global__ __launch_bounds__(256, 4) void k_edge_mfma(
    int layer, int write_e, int accum_stats,
    void* __restrict__ e, int et, void* __restrict__ e_ij, int jt,
    const int* __restrict__ esrc, const int* __restrict__ edst,
    const int* __restrict__ eattr, const float* __restrict__ bond,
    const ushort_t* __restrict__ WCf, const float* __restrict__ bC,
    const void* __restrict__ Dx, const void* __restrict__ Ex, int nt,
    const float* __restrict__ stats_prev,
    const float* __restrict__ gE, const float* __restrict__ bEb,
    float* __restrict__ stats_out) {
    // union: bf16 A-tile [64][PADA] (17408B) then fp32 out-tile [64][PADO] (33792B)
    __shared__ __align__(16) char Ub[64 * PADO * 4];
    ushort_t* eA = (ushort_t*)Ub;
    float* OT = (float*)Ub;

    int tid = threadIdx.x;
    int lane = tid & 63, wid = tid >> 6;
    int ln15 = lane & 15, quad = lane >> 4;
    size_t base = (size_t)blockIdx.x * 64;
    const float invE = 1.0f / (float)EE;

    // ---- stage: 32 elems/thread in 4 groups of 8 ----
    {
        int row = tid >> 2;
        int cb = (tid & 3) * 32;
        size_t grow = base + row;
        bool v = grow < (size_t)EE;
        int a0 = 0, a1 = 0, a2 = 0;
        if (v && layer == 0) {
            a0 = eattr[grow * 3 + 0];
            a1 = eattr[grow * 3 + 1];
            a2 = eattr[grow * 3 + 2];
        }
#pragma unroll
        for (int g = 0; g < 4; g++) {
            int k0 = cb + g * 8;
            float vals[8];
            if (v) {
                if (layer == 0) {
#pragma unroll
                    for (int j = 0; j < 8; j++) {
                        int k = k0 + j;
                        vals[j] = bond[a0 * 128 + k] + bond[(37 + a1) * 128 + k]
                                + bond[(74 + a2) * 128 + k];
                    }
                } else {
                    float ep[8], hij[8];
                    load8(e, grow * 128 + k0, et, ep);
                    load8(e_ij, grow * 128 + k0, jt, hij);
#pragma unroll
                    for (int j = 0; j < 8; j++) {
                        int k = k0 + j;
                        float m = stats_prev[k] * invE;
                        float var = stats_prev[128 + k] * invE - m * m;
                        float y = gE[k] * (hij[j] - m) * rsqrtf(var + 1e-5f) + bEb[k];
                        vals[j] = ep[j] + gelu_tanh(y);
                    }
                }
                if (write_e) store8(e, grow * 128 + k0, et, vals);
            } else {
#pragma unroll
                for (int j = 0; j < 8; j++) vals[j] = 0.0f;
            }
            ushort_t tmp[8];
#pragma unroll
            for (int j = 0; j < 8; j++) tmp[j] = f2b_bits(vals[j]);
            *(uint4*)&eA[row * PADA + k0] = *(const uint4*)tmp;
        }
    }
    __syncthreads();

    // ---- MFMA GEMM: wave w -> rows [16w,16w+16), tiles n=0..7 ----
    f4v acc[8];
#pragma unroll
    for (int n = 0; n < 8; n++) acc[n] = (f4v)(0.0f);
    {
        const ushort_t* arow = &eA[(wid * 16 + ln15) * PADA + quad * 8];
#pragma unroll
        for (int kc = 0; kc < 4; kc++) {
            s8v a = *(const s8v*)(arow + kc * 32);
#pragma unroll
            for (int n = 0; n < 8; n++) {
                s8v b = *(const s8v*)(WCf + ((size_t)(kc * 8 + n) * 64 + lane) * 8);
                acc[n] = __builtin_amdgcn_mfma_f32_16x16x32_bf16(a, b, acc[n], 0, 0, 0);
            }
        }
    }
    __syncthreads();   // A-tile dead; OT region now live

    // ---- epilogue: + bC + Dx[dst] + Ex[src] -> fp32 LDS out tile ----
    {
        float bcv[8];
#pragma unroll
        for (int n = 0; n < 8; n++) bcv[n] = bC[n * 16 + ln15];
#pragma unroll
        for (int rr = 0; rr < 4; rr++) {
            int lrow = wid * 16 + quad * 4 + rr;
            size_t grow = base + lrow;
            bool v = grow < (size_t)EE;
            int dn = v ? edst[grow] : 0;
            int sn = v ? esrc[grow] : 0;
#pragma unroll
            for (int n = 0; n < 8; n++) {
                int col = n * 16 + ln15;
                float val = acc[n][rr] + bcv[n]
                          + loadT(Dx, (size_t)dn * 128 + col, nt)
                          + loadT(Ex, (size_t)sn * 128 + col, nt);
                OT[lrow * PADO + col] = v ? val : 0.0f;
            }
        }
    }
    __syncthreads();

    // ---- BN-e stats (fp32) ----
    if (accum_stats) {
        int c = tid & 127, hh = tid >> 7;
        float s = 0.0f, q = 0.0f;
        for (int r = 0; r < 64; r++) {
            float x = OT[r * PADO + c];
            s += x;
            q += x * x;
        }
        if (hh == 0) atomicAdd(&stats_out[c], s);
        else         atomicAdd(&stats_out[128 + c], q);
    }

    // ---- coalesced e_ij store ----
    {
        int row = tid >> 2;
        int cb = (tid & 3) * 32;
        size_t grow = base + row;
        if (grow < (size_t)EE) {
#pragma unroll
            for (int g = 0; g < 4; g++) {
                int k0 = cb + g * 8;
                float vals[8];
#pragma unroll
                for (int j = 0; j < 8; j++) vals[j] = OT[row * PADO + k0 + j];
                store8(e_ij, grow * 128 + k0, jt, vals);
            }
        }
    }
}

// ---------------- K3: CSR aggregation (wave per node) ----------------
__global__ __launch_bounds__(256) void k_aggr(
    const int* __restrict__ row_ptr, const int* __restrict__ perm,
    const int* __restrict__ esrc, const void* __restrict__ e_ij, int jt,
    const void* __restrict__ Bx, const void* __restrict__ Ax, int nt,
    void* __restrict__ x_new) {
    int tid = threadIdx.x, wid = tid >> 6, lane = tid & 63;
    int n = blockIdx.x * 4 + wid;
    if (n >= NN) return;
    int s0 = row_ptr[n], s1 = row_ptr[n + 1];
    float num0 = 0.0f, num1 = 0.0f, den0 = 0.0f, den1 = 0.0f;
    for (int i = s0; i < s1; i++) {
        int eid = perm[i];
        int src = esrc[eid];
        float g0 = sigmoidf_(loadT(e_ij, (size_t)eid * 128 + lane, jt));
        float g1 = sigmoidf_(loadT(e_ij, (size_t)eid * 128 + 64 + lane, jt));
        num0 += g0 * loadT(Bx, (size_t)src * 128 + lane, nt);
        num1 += g1 * loadT(Bx, (size_t)src * 128 + 64 + lane, nt);
        den0 += g0;
        den1 += g1;
    }
    float a0 = loadT(Ax, (size_t)n * 128 + lane, nt);
    float a1 = loadT(Ax, (size_t)n * 128 + 64 + lane, nt);
    storeT(x_new, (size_t)n * 128 + lane,      nt, a0 + num0 / (den0 + 1e-6f));
    storeT(x_new, (size_t)n * 128 + 64 + lane, nt, a1 + num1 / (den1 + 1e-6f));
}

// ---------------- K4: per-channel stats of x_new ----------------
__global__ __launch_bounds__(256) void k_xstats(const void* __restrict__ x_new, int nt,
                                                float* __restrict__ stats) {
    int tid = threadIdx.x;
    int c = tid & 127, hh = tid >> 7;
    float s = 0.0f, q = 0.0f;
    for (int r = blockIdx.x * 2 + hh; r < NN; r += (int)gridDim.x * 2) {
        float v = loadT(x_new, (size_t)r * 128 + c, nt);
        s += v;
        q += v * v;
    }
    atomicAdd(&stats[c], s);
    atomicAdd(&stats[128 + c], q);
}

// ---------------- K5: x update ----------------
__global__ __launch_bounds__(256) void k_xupd(
    const void* __restrict__ xin, int xt,
    const void* __restrict__ x_new, int nt,
    const float* __restrict__ stats, const float* __restrict__ g,
    const float* __restrict__ bb, void* __restrict__ xout, int ot) {
    int idx = blockIdx.x * 256 + threadIdx.x;
    if (idx >= NN * 128) return;
    int c = idx & 127;
    const float invN = 1.0f / (float)NN;
    float m = stats[c] * invN;
    float var = stats[128 + c] * invN - m * m;
    float y = g[c] * (loadT(x_new, idx, nt) - m) * rsqrtf(var + 1e-5f) + bb[c];
    float xi = loadT(xin, idx, xt);
    storeT(xout, idx, ot, xi + gelu_tanh(y));
}

extern "C" void kernel_launch(void* const* d_in, const int* in_sizes, int n_in,
                              void* d_out, int out_size, void* d_ws, size_t ws_size,
                              hipStream_t stream) {
    const float* X_n  = (const float*)d_in[0];
    const int*  eidx  = (const int*)d_in[2];
    const int*  eattr = (const int*)d_in[3];
    const float* bond = (const float*)d_in[4];
    const float* WA = (const float*)d_in[5];  const float* bA = (const float*)d_in[6];
    const float* WB = (const float*)d_in[7];  const float* bB = (const float*)d_in[8];
    const float* WC = (const float*)d_in[9];  const float* bC = (const float*)d_in[10];
    const float* WD = (const float*)d_in[11]; const float* bD = (const float*)d_in[12];
    const float* WE = (const float*)d_in[13]; const float* bE = (const float*)d_in[14];
    const float* bn_x_g = (const float*)d_in[15];
    const float* bn_x_b = (const float*)d_in[16];
    const float* bn_e_g = (const float*)d_in[17];
    const float* bn_e_b = (const float*)d_in[18];

    const int* esrc = eidx;
    const int* edst = eidx + EE;

    // ---- precision ladder ----
    auto tsz = [](int t) -> size_t { return t == 0 ? 4 : (t == 1 ? 2 : 1); };
    int cfgs[7][4] = {
        {1, 1, 0, 0},   // ~400 MB
        {1, 1, 1, 0},   // ~374 MB
        {1, 2, 0, 0},   // ~320 MB
        {1, 2, 1, 0},   // ~294 MB
        {2, 2, 0, 0},   // ~240 MB
        {2, 2, 1, 0},   // ~214 MB
        {2, 2, 1, 1},   // ~202 MB
    };
    const size_t ND = (size_t)NN * DD, ED = (size_t)EE * DD;
    int chosen = -1;
    for (int c = 0; c < 7; c++) {
        size_t need = ED * (tsz(cfgs[c][0]) + tsz(cfgs[c][1]))
                    + ND * (2 * tsz(cfgs[c][2]) + tsz(cfgs[c][3]))
                    + 2048 * 4
                    + ((size_t)NN * 3 + 1 + EE) * 4
                    + 4 * 16384 * 2          /* WCf frag buffer */
                    + 20 * 256;
        if (ws_size >= need) { chosen = c; break; }
    }
    if (chosen < 0) return;
    int et = cfgs[chosen][0], jt = cfgs[chosen][1], nt = cfgs[chosen][2], xt = cfgs[chosen][3];

    size_t off = 0;
    auto carve = [&](size_t bytes) -> void* {
        void* p = (char*)d_ws + off;
        off += (bytes + 255) & ~(size_t)255;
        return p;
    };
    float* e_stats = (float*)carve(1024 * 4);
    float* x_stats = (float*)carve(1024 * 4);
    int* deg     = (int*)carve((size_t)NN * 4);
    int* row_ptr = (int*)carve(((size_t)NN + 1) * 4);
    int* cursor  = (int*)carve((size_t)NN * 4);
    int* perm    = (int*)carve((size_t)EE * 4);
    ushort_t* WCf = (ushort_t*)carve(4 * 16384 * 2);
    void* x_buf  = carve(ND * tsz(xt));
    void* P0     = carve(ND * tsz(nt));     // Dx then Ax; x_new aliases P0
    void* P1     = carve(ND * tsz(nt));     // Ex then Bx
    void* e      = carve(ED * tsz(et));
    void* e_ij   = carve(ED * tsz(jt));
    void* x_new  = P0;

    k_zero<<<(NN + 255) / 256, 256, 0, stream>>>(deg, NN);
    k_zero<<<8, 256, 0, stream>>>((int*)e_stats, 2048);
    k_wprep<<<256, 256, 0, stream>>>(WC, WCf);

    int egrid = (EE + 255) / 256;
    k_count<<<egrid, 256, 0, stream>>>(edst, deg);
    k_scan<<<1, 1024, 0, stream>>>(deg, row_ptr, cursor);
    k_scatter<<<egrid, 256, 0, stream>>>(edst, cursor, perm);

    const int ngemm_grid = (NN + 63) / 64;
    const int edge_grid  = (EE + 63) / 64;
    const int aggr_grid  = (NN + 3) / 4;
    const int upd_grid   = (NN * DD + 255) / 256;

    for (int l = 0; l < LL; l++) {
        const void* xin = (l == 0) ? (const void*)X_n : (const void*)x_buf;
        int xint = (l == 0) ? 0 : xt;

        // phase A: Dx -> P0, Ex -> P1
        k_node_gemm2<<<ngemm_grid, 256, 0, stream>>>(
            xin, xint,
            WD + (size_t)l * DD * DD, WE + (size_t)l * DD * DD,
            bD + l * DD, bE + l * DD, P0, P1, nt);

        int prev = (l > 0) ? (l - 1) : 0;
        k_edge_mfma<<<edge_grid, 256, 0, stream>>>(
            l, (l < 3) ? 1 : 0, (l < 3) ? 1 : 0,
            e, et, e_ij, jt, esrc, edst, eattr, bond,
            WCf + (size_t)l * 16384, bC + l * DD,
            P0, P1, nt,
            e_stats + prev * 256, bn_e_g + prev * DD, bn_e_b + prev * DD,
            e_stats + l * 256);

        // phase B: Ax -> P0, Bx -> P1
        k_node_gemm2<<<ngemm_grid, 256, 0, stream>>>(
            xin, xint,
            WA + (size_t)l * DD * DD, WB + (size_t)l * DD * DD,
            bA + l * DD, bB + l * DD, P0, P1, nt);

        k_aggr<<<aggr_grid, 256, 0, stream>>>(row_ptr, perm, esrc, e_ij, jt, P1, P0, nt, x_new);
        k_xstats<<<256, 256, 0, stream>>>(x_new, nt, x_stats + l * 256);

        void* xo = (l == 3) ? d_out : x_buf;
        int ot = (l == 3) ? 0 : xt;
        k_xupd<<<upd_grid, 256, 0, stream>>>(xin, xint, x_new, nt, x_stats + l * 256,
                                             bn_x_g + l * DD, bn_x_b + l * DD, xo, ot);
    }
}

// Round 8
// 3615.691 us; speedup vs baseline: 1.8762x; 1.0608x over previous
//
#include <hip/hip_runtime.h>
#include <hip/hip_bf16.h>

#define LL 4
#define NN 50000
#define EE 625000
#define DD 128

#define PADA 136   // bf16 A-tile row pitch (elements)
#define PADO 132   // fp32 out-tile row pitch (elements)

typedef __hip_bfloat16 bf16;
typedef unsigned char u8;
typedef unsigned short ushort_t;
typedef unsigned int uint_t;
typedef __attribute__((ext_vector_type(8))) short s8v;   // 8 bf16 (4 VGPRs)
typedef __attribute__((ext_vector_type(4))) float f4v;   // 4 fp32 acc

__device__ __forceinline__ float b2f(bf16 v) { return __bfloat162float(v); }
__device__ __forceinline__ ushort_t f2b_bits(float v) {
    bf16 h = __float2bfloat16(v);
    return *reinterpret_cast<ushort_t*>(&h);
}
__device__ __forceinline__ float bits2f(ushort_t u) {
    bf16 h;
    *reinterpret_cast<ushort_t*>(&h) = u;
    return __bfloat162float(h);
}

// ---- manual OCP fp8 e4m3fn codec ----
__device__ __forceinline__ u8 f2e4m3(float x) {
    if (x != x) return 0x7f;
    u8 s = (x < 0.0f) ? 0x80 : 0x00;
    float a = fabsf(x);
    if (a >= 448.0f) return s | 0x7e;
    if (a < 0.0009765625f) return s;
    int e;
    float m = frexpf(a, &e);
    int E = e - 1;
    if (E < -6) {
        int f = (int)rintf(a * 512.0f);
        if (f >= 8) return s | 0x08;
        return s | (u8)f;
    }
    int f = (int)rintf(m * 16.0f);
    if (f == 16) { E++; f = 8; }
    if (E > 8) return s | 0x7e;
    return s | (u8)(((E + 7) << 3) | (f & 7));
}
__device__ __forceinline__ float e4m32f(u8 v) {
    int ex = (v >> 3) & 0xF, man = v & 7;
    float a;
    if (ex == 0) a = (float)man * 0.001953125f;
    else a = ldexpf(1.0f + (float)man * 0.125f, ex - 7);
    return (v & 0x80) ? -a : a;
}

// ---- typed scalar load/store: t=0 fp32, 1 bf16, 2 fp8 ----
__device__ __forceinline__ float loadT(const void* p, size_t i, int t) {
    if (t == 0) return ((const float*)p)[i];
    if (t == 1) return b2f(((const bf16*)p)[i]);
    return e4m32f(((const u8*)p)[i]);
}
__device__ __forceinline__ void storeT(void* p, size_t i, int t, float v) {
    if (t == 0) ((float*)p)[i] = v;
    else if (t == 1) ((bf16*)p)[i] = __float2bfloat16(v);
    else ((u8*)p)[i] = f2e4m3(v);
}

// ---- pair load/store (i must be 2-aligned) ----
__device__ __forceinline__ void load2(const void* p, size_t i, int t, float* v) {
    if (t == 0) {
        float2 f = *(const float2*)((const float*)p + i);
        v[0] = f.x; v[1] = f.y;
    } else if (t == 1) {
        uint_t u = *(const uint_t*)((const ushort_t*)p + i);
        v[0] = bits2f((ushort_t)(u & 0xffff));
        v[1] = bits2f((ushort_t)(u >> 16));
    } else {
        ushort_t u = *(const ushort_t*)((const u8*)p + i);
        v[0] = e4m32f((u8)(u & 0xff));
        v[1] = e4m32f((u8)(u >> 8));
    }
}
__device__ __forceinline__ void store2(void* p, size_t i, int t, const float* v) {
    if (t == 0) {
        float2 f; f.x = v[0]; f.y = v[1];
        *(float2*)((float*)p + i) = f;
    } else if (t == 1) {
        uint_t u = (uint_t)f2b_bits(v[0]) | ((uint_t)f2b_bits(v[1]) << 16);
        *(uint_t*)((ushort_t*)p + i) = u;
    } else {
        ushort_t u = (ushort_t)(f2e4m3(v[0]) | (f2e4m3(v[1]) << 8));
        *(ushort_t*)((u8*)p + i) = u;
    }
}

// ---- 8-wide vector load/store (i must be 8-aligned) ----
__device__ __forceinline__ void load8(const void* p, size_t i, int t, float* v) {
    if (t == 1) {
        uint4 u = *(const uint4*)((const ushort_t*)p + i);
        const ushort_t* us = (const ushort_t*)&u;
#pragma unroll
        for (int j = 0; j < 8; j++) v[j] = bits2f(us[j]);
    } else if (t == 2) {
        uint2 u = *(const uint2*)((const u8*)p + i);
        const u8* b = (const u8*)&u;
#pragma unroll
        for (int j = 0; j < 8; j++) v[j] = e4m32f(b[j]);
    } else {
        const float* f = (const float*)p + i;
#pragma unroll
        for (int j = 0; j < 8; j++) v[j] = f[j];
    }
}
__device__ __forceinline__ void store8(void* p, size_t i, int t, const float* v) {
    if (t == 1) {
        ushort_t tmp[8];
#pragma unroll
        for (int j = 0; j < 8; j++) tmp[j] = f2b_bits(v[j]);
        *(uint4*)((ushort_t*)p + i) = *(const uint4*)tmp;
    } else if (t == 2) {
        u8 tmp[8];
#pragma unroll
        for (int j = 0; j < 8; j++) tmp[j] = f2e4m3(v[j]);
        *(uint2*)((u8*)p + i) = *(const uint2*)tmp;
    } else {
        float* f = (float*)p + i;
#pragma unroll
        for (int j = 0; j < 8; j++) f[j] = v[j];
    }
}

// gelu(approximate=True) via exact identity 0.5v(1+tanh(u)) = v*sigmoid(2u)
__device__ __forceinline__ float gelu_tanh(float v) {
    const float c2 = 1.5957691216057308f;   // 2*sqrt(2/pi)
    float u = c2 * (v + 0.044715f * v * v * v);
    return v / (1.0f + __expf(-u));
}
__device__ __forceinline__ float sigmoidf_(float x) {
    return 1.0f / (1.0f + __expf(-x));
}

// ---------------- utility ----------------
__global__ __launch_bounds__(256) void k_zero(int* __restrict__ p, int n) {
    int i = blockIdx.x * 256 + threadIdx.x;
    if (i < n) p[i] = 0;
}

// ---------------- CSR build ----------------
__global__ __launch_bounds__(256) void k_count(const int* __restrict__ edst, int* __restrict__ deg) {
    int e = blockIdx.x * 256 + threadIdx.x;
    if (e < EE) atomicAdd(&deg[edst[e]], 1);
}

__global__ __launch_bounds__(1024) void k_scan(const int* __restrict__ deg, int* __restrict__ row_ptr,
                                               int* __restrict__ cursor) {
    __shared__ int temp[1024];
    __shared__ int carry;
    int tid = threadIdx.x;
    if (tid == 0) carry = 0;
    __syncthreads();
    for (int base = 0; base < NN; base += 1024) {
        int i = base + tid;
        int v = (i < NN) ? deg[i] : 0;
        temp[tid] = v;
        __syncthreads();
        for (int off = 1; off < 1024; off <<= 1) {
            int t = (tid >= off) ? temp[tid - off] : 0;
            __syncthreads();
            temp[tid] += t;
            __syncthreads();
        }
        int excl = temp[tid] - v + carry;
        if (i < NN) { row_ptr[i] = excl; cursor[i] = excl; }
        __syncthreads();
        if (tid == 1023) carry += temp[1023];
        __syncthreads();
    }
    if (tid == 0) row_ptr[NN] = carry;
}

__global__ __launch_bounds__(256) void k_scatter(const int* __restrict__ edst, int* __restrict__ cursor,
                                                 int* __restrict__ perm) {
    int e = blockIdx.x * 256 + threadIdx.x;
    if (e < EE) {
        int p = atomicAdd(&cursor[edst[e]], 1);
        perm[p] = e;
    }
}

// ---------------- W prep: WC -> bf16 B-fragment order ----------------
__global__ __launch_bounds__(256) void k_wprep(const float* __restrict__ WC, ushort_t* __restrict__ WCf) {
    int tid = blockIdx.x * 256 + threadIdx.x;
    if (tid >= 4 * 32 * 64 * 8) return;
    int j = tid & 7;
    int l6 = (tid >> 3) & 63;
    int f = (tid >> 9) & 31;
    int layer = tid >> 14;
    int kc = f >> 3, n = f & 7;
    int k = kc * 32 + (l6 >> 4) * 8 + j;
    int col = n * 16 + (l6 & 15);
    WCf[tid] = f2b_bits(WC[(size_t)layer * 16384 + k * 128 + col]);
}

// ---------------- K1: node GEMM, 2 matrices per call ----------------
__global__ __launch_bounds__(256) void k_node_gemm2(
    const void* __restrict__ x, int xt,
    const float* __restrict__ WX, const float* __restrict__ WY,
    const float* __restrict__ bX, const float* __restrict__ bY,
    void* __restrict__ OX, void* __restrict__ OY, int nt) {
    __shared__ float smem[12352];          // w_lds[64][128] + x_lds[64][65]
    float* w_lds = smem;
    float* x_lds = smem + 8192;
    int tid = threadIdx.x, wid = tid >> 6, lane = tid & 63;
    int base = blockIdx.x * 64;
    for (int m = 0; m < 2; m++) {
        const float* W = (m == 0) ? WX : WY;
        const float* bb = (m == 0) ? bX : bY;
        void* O = (m == 0) ? OX : OY;
        float acc[32];
#pragma unroll
        for (int jj = 0; jj < 32; jj++) acc[jj] = bb[wid * 32 + jj];
        for (int h = 0; h < 2; h++) {
            __syncthreads();
            for (int idx = tid; idx < 8192; idx += 256)
                w_lds[idx] = W[(h * 64 + (idx >> 7)) * 128 + (idx & 127)];
            for (int idx = tid; idx < 4096; idx += 256) {
                int r = idx >> 6, kl = idx & 63;
                int n = base + r;
                float xv = 0.0f;
                if (n < NN) xv = loadT(x, (size_t)n * 128 + h * 64 + kl, xt);
                x_lds[r * 65 + kl] = xv;
            }
            __syncthreads();
            const float4* w4 = (const float4*)w_lds;
            for (int kl = 0; kl < 64; kl++) {
                float xk = x_lds[lane * 65 + kl];
#pragma unroll
                for (int j4 = 0; j4 < 8; j4++) {
                    float4 wv = w4[kl * 32 + wid * 8 + j4];
                    acc[j4 * 4 + 0] += xk * wv.x;
                    acc[j4 * 4 + 1] += xk * wv.y;
                    acc[j4 * 4 + 2] += xk * wv.z;
                    acc[j4 * 4 + 3] += xk * wv.w;
                }
            }
        }
        __syncthreads();
#pragma unroll
        for (int jj = 0; jj < 32; jj++) smem[lane * 129 + wid * 32 + jj] = acc[jj];
        __syncthreads();
        for (int idx = tid; idx < 8192; idx += 256) {
            int r = idx >> 7, k = idx & 127;
            if (base + r < NN) storeT(O, (size_t)(base + r) * 128 + k, nt, smem[r * 129 + k]);
        }
    }
}

// ---------------- K2: fused edge pass (MFMA) ----------------
__global__ __launch_bounds__(256, 4) void k_edge_mfma(
    int layer, int write_e, int accum_stats,
    void* __restrict__ e, int et, void* __restrict__ e_ij, int jt,
    const int* __restrict__ esrc, const int* __restrict__ edst,
    const int* __restrict__ eattr, const float* __restrict__ bond,
    const ushort_t* __restrict__ WCf, const float* __restrict__ bC,
    const void* __restrict__ Dx, const void* __restrict__ Ex, int nt,
    const float* __restrict__ stats_prev,
    const float* __restrict__ gE, const float* __restrict__ bEb,
    float* __restrict__ stats_out) {
    // union: bf16 A-tile [64][PADA] (17408B) then fp32 out-tile [64][PADO] (33792B)
    __shared__ __align__(16) char Ub[64 * PADO * 4];
    __shared__ float bnS[128], bnH[128];
    ushort_t* eA = (ushort_t*)Ub;
    float* OT = (float*)Ub;

    int tid = threadIdx.x;
    int lane = tid & 63, wid = tid >> 6;
    int ln15 = lane & 15, quad = lane >> 4;
    size_t base = (size_t)blockIdx.x * 64;
    const float invE = 1.0f / (float)EE;

    // per-channel BN scale/shift (valid for layer>0; layer 0 ignores)
    if (tid < 128) {
        float m = stats_prev[tid] * invE;
        float var = stats_prev[128 + tid] * invE - m * m;
        float s = gE[tid] * rsqrtf(var + 1e-5f);
        bnS[tid] = s;
        bnH[tid] = bEb[tid] - m * s;
    }
    __syncthreads();

    // ---- stage: 32 elems/thread in 4 groups of 8 ----
    {
        int row = tid >> 2;
        int cb = (tid & 3) * 32;
        size_t grow = base + row;
        bool v = grow < (size_t)EE;
        int a0 = 0, a1 = 0, a2 = 0;
        if (v && layer == 0) {
            a0 = eattr[grow * 3 + 0];
            a1 = eattr[grow * 3 + 1];
            a2 = eattr[grow * 3 + 2];
        }
#pragma unroll
        for (int g = 0; g < 4; g++) {
            int k0 = cb + g * 8;
            float vals[8];
            if (v) {
                if (layer == 0) {
#pragma unroll
                    for (int j = 0; j < 8; j++) {
                        int k = k0 + j;
                        vals[j] = bond[a0 * 128 + k] + bond[(37 + a1) * 128 + k]
                                + bond[(74 + a2) * 128 + k];
                    }
                } else {
                    float ep[8], hij[8];
                    load8(e, grow * 128 + k0, et, ep);
                    load8(e_ij, grow * 128 + k0, jt, hij);
#pragma unroll
                    for (int j = 0; j < 8; j++) {
                        int k = k0 + j;
                        float y = bnS[k] * hij[j] + bnH[k];
                        vals[j] = ep[j] + gelu_tanh(y);
                    }
                }
                if (write_e) store8(e, grow * 128 + k0, et, vals);
            } else {
#pragma unroll
                for (int j = 0; j < 8; j++) vals[j] = 0.0f;
            }
            ushort_t tmp[8];
#pragma unroll
            for (int j = 0; j < 8; j++) tmp[j] = f2b_bits(vals[j]);
            *(uint4*)&eA[row * PADA + k0] = *(const uint4*)tmp;
        }
    }
    __syncthreads();

    // ---- MFMA GEMM: wave w -> rows [16w,16w+16), tiles n=0..7 ----
    f4v acc[8];
#pragma unroll
    for (int n = 0; n < 8; n++) acc[n] = (f4v)(0.0f);
    {
        const ushort_t* arow = &eA[(wid * 16 + ln15) * PADA + quad * 8];
#pragma unroll
        for (int kc = 0; kc < 4; kc++) {
            s8v a = *(const s8v*)(arow + kc * 32);
#pragma unroll
            for (int n = 0; n < 8; n++) {
                s8v b = *(const s8v*)(WCf + ((size_t)(kc * 8 + n) * 64 + lane) * 8);
                acc[n] = __builtin_amdgcn_mfma_f32_16x16x32_bf16(a, b, acc[n], 0, 0, 0);
            }
        }
    }
    __syncthreads();   // A-tile dead; OT region now live

    // ---- E1: cooperative coalesced Dx[dst]+Ex[src] rows -> OT ----
    {
        int row = tid >> 2;
        int cb = (tid & 3) * 32;
        size_t grow = base + row;
        bool v = grow < (size_t)EE;
        int dn = v ? edst[grow] : 0;
        int sn = v ? esrc[grow] : 0;
#pragma unroll
        for (int g = 0; g < 4; g++) {
            int k0 = cb + g * 8;
            float d8[8], x8[8];
            if (v) {
                load8(Dx, (size_t)dn * 128 + k0, nt, d8);
                load8(Ex, (size_t)sn * 128 + k0, nt, x8);
#pragma unroll
                for (int j = 0; j < 8; j++) d8[j] += x8[j];
            } else {
#pragma unroll
                for (int j = 0; j < 8; j++) d8[j] = 0.0f;
            }
#pragma unroll
            for (int j = 0; j < 8; j++) OT[row * PADO + k0 + j] = d8[j];
        }
    }
    __syncthreads();

    // ---- E2: add MFMA accumulator + bias in C-layout ----
    {
        float bcv[8];
#pragma unroll
        for (int n = 0; n < 8; n++) bcv[n] = bC[n * 16 + ln15];
#pragma unroll
        for (int rr = 0; rr < 4; rr++) {
            int lrow = wid * 16 + quad * 4 + rr;
            size_t grow = base + lrow;
            if (grow < (size_t)EE) {
#pragma unroll
                for (int n = 0; n < 8; n++) {
                    int col = n * 16 + ln15;
                    OT[lrow * PADO + col] += acc[n][rr] + bcv[n];
                }
            }
        }
    }
    __syncthreads();

    // ---- BN-e stats (fp32) ----
    if (accum_stats) {
        int c = tid & 127, hh = tid >> 7;
        float s = 0.0f, q = 0.0f;
        for (int r = 0; r < 64; r++) {
            float x = OT[r * PADO + c];
            s += x;
            q += x * x;
        }
        if (hh == 0) atomicAdd(&stats_out[c], s);
        else         atomicAdd(&stats_out[128 + c], q);
    }

    // ---- coalesced e_ij store ----
    {
        int row = tid >> 2;
        int cb = (tid & 3) * 32;
        size_t grow = base + row;
        if (grow < (size_t)EE) {
#pragma unroll
            for (int g = 0; g < 4; g++) {
                int k0 = cb + g * 8;
                float vals[8];
#pragma unroll
                for (int j = 0; j < 8; j++) vals[j] = OT[row * PADO + k0 + j];
                store8(e_ij, grow * 128 + k0, jt, vals);
            }
        }
    }
}

// ---------------- K3: CSR aggregation (wave per node, column pairs) ----------------
__global__ __launch_bounds__(256) void k_aggr(
    const int* __restrict__ row_ptr, const int* __restrict__ perm,
    const int* __restrict__ esrc, const void* __restrict__ e_ij, int jt,
    const void* __restrict__ Bx, const void* __restrict__ Ax, int nt,
    void* __restrict__ x_new) {
    int tid = threadIdx.x, wid = tid >> 6, lane = tid & 63;
    int n = blockIdx.x * 4 + wid;
    if (n >= NN) return;
    int s0 = row_ptr[n], s1 = row_ptr[n + 1];
    int c0 = 2 * lane;
    float num0 = 0.0f, num1 = 0.0f, den0 = 0.0f, den1 = 0.0f;
    int i = s0;
    int eid_n = 0, src_n = 0;
    if (i < s1) { eid_n = perm[i]; src_n = esrc[eid_n]; }
    while (i < s1) {
        int eid = eid_n, src = src_n;
        int ip = i + 1;
        if (ip < s1) { eid_n = perm[ip]; src_n = esrc[eid_n]; }
        float h[2], b[2];
        load2(e_ij, (size_t)eid * 128 + c0, jt, h);
        load2(Bx, (size_t)src * 128 + c0, nt, b);
        float g0 = sigmoidf_(h[0]);
        float g1 = sigmoidf_(h[1]);
        num0 += g0 * b[0];
        num1 += g1 * b[1];
        den0 += g0;
        den1 += g1;
        i = ip;
    }
    float a[2];
    load2(Ax, (size_t)n * 128 + c0, nt, a);
    float o[2] = { a[0] + num0 / (den0 + 1e-6f), a[1] + num1 / (den1 + 1e-6f) };
    store2(x_new, (size_t)n * 128 + c0, nt, o);
}

// ---------------- K4: per-channel stats of x_new ----------------
__global__ __launch_bounds__(256) void k_xstats(const void* __restrict__ x_new, int nt,
                                                float* __restrict__ stats) {
    int tid = threadIdx.x;
    int c = tid & 127, hh = tid >> 7;
    float s = 0.0f, q = 0.0f;
    for (int r = blockIdx.x * 2 + hh; r < NN; r += (int)gridDim.x * 2) {
        float v = loadT(x_new, (size_t)r * 128 + c, nt);
        s += v;
        q += v * v;
    }
    atomicAdd(&stats[c], s);
    atomicAdd(&stats[128 + c], q);
}

// ---------------- K5: x update ----------------
__global__ __launch_bounds__(256) void k_xupd(
    const void* __restrict__ xin, int xt,
    const void* __restrict__ x_new, int nt,
    const float* __restrict__ stats, const float* __restrict__ g,
    const float* __restrict__ bb, void* __restrict__ xout, int ot) {
    __shared__ float sc[128], sh[128];
    int tid = threadIdx.x;
    if (tid < 128) {
        const float invN = 1.0f / (float)NN;
        float m = stats[tid] * invN;
        float var = stats[128 + tid] * invN - m * m;
        float s = g[tid] * rsqrtf(var + 1e-5f);
        sc[tid] = s;
        sh[tid] = bb[tid] - m * s;
    }
    __syncthreads();
    int idx = blockIdx.x * 256 + tid;
    if (idx >= NN * 128) return;
    int c = idx & 127;
    float y = sc[c] * loadT(x_new, idx, nt) + sh[c];
    float xi = loadT(xin, idx, xt);
    storeT(xout, idx, ot, xi + gelu_tanh(y));
}

extern "C" void kernel_launch(void* const* d_in, const int* in_sizes, int n_in,
                              void* d_out, int out_size, void* d_ws, size_t ws_size,
                              hipStream_t stream) {
    const float* X_n  = (const float*)d_in[0];
    const int*  eidx  = (const int*)d_in[2];
    const int*  eattr = (const int*)d_in[3];
    const float* bond = (const float*)d_in[4];
    const float* WA = (const float*)d_in[5];  const float* bA = (const float*)d_in[6];
    const float* WB = (const float*)d_in[7];  const float* bB = (const float*)d_in[8];
    const float* WC = (const float*)d_in[9];  const float* bC = (const float*)d_in[10];
    const float* WD = (const float*)d_in[11]; const float* bD = (const float*)d_in[12];
    const float* WE = (const float*)d_in[13]; const float* bE = (const float*)d_in[14];
    const float* bn_x_g = (const float*)d_in[15];
    const float* bn_x_b = (const float*)d_in[16];
    const float* bn_e_g = (const float*)d_in[17];
    const float* bn_e_b = (const float*)d_in[18];

    const int* esrc = eidx;
    const int* edst = eidx + EE;

    // ---- precision ladder ----
    auto tsz = [](int t) -> size_t { return t == 0 ? 4 : (t == 1 ? 2 : 1); };
    int cfgs[7][4] = {
        {1, 1, 0, 0},   // ~400 MB
        {1, 1, 1, 0},   // ~374 MB
        {1, 2, 0, 0},   // ~320 MB
        {1, 2, 1, 0},   // ~294 MB
        {2, 2, 0, 0},   // ~240 MB
        {2, 2, 1, 0},   // ~214 MB
        {2, 2, 1, 1},   // ~202 MB
    };
    const size_t ND = (size_t)NN * DD, ED = (size_t)EE * DD;
    int chosen = -1;
    for (int c = 0; c < 7; c++) {
        size_t need = ED * (tsz(cfgs[c][0]) + tsz(cfgs[c][1]))
                    + ND * (2 * tsz(cfgs[c][2]) + tsz(cfgs[c][3]))
                    + 2048 * 4
                    + ((size_t)NN * 3 + 1 + EE) * 4
                    + 4 * 16384 * 2
                    + 20 * 256;
        if (ws_size >= need) { chosen = c; break; }
    }
    if (chosen < 0) return;
    int et = cfgs[chosen][0], jt = cfgs[chosen][1], nt = cfgs[chosen][2], xt = cfgs[chosen][3];

    size_t off = 0;
    auto carve = [&](size_t bytes) -> void* {
        void* p = (char*)d_ws + off;
        off += (bytes + 255) & ~(size_t)255;
        return p;
    };
    float* e_stats = (float*)carve(1024 * 4);
    float* x_stats = (float*)carve(1024 * 4);
    int* deg     = (int*)carve((size_t)NN * 4);
    int* row_ptr = (int*)carve(((size_t)NN + 1) * 4);
    int* cursor  = (int*)carve((size_t)NN * 4);
    int* perm    = (int*)carve((size_t)EE * 4);
    ushort_t* WCf = (ushort_t*)carve(4 * 16384 * 2);
    void* x_buf  = carve(ND * tsz(xt));
    void* P0     = carve(ND * tsz(nt));     // Dx then Ax; x_new aliases P0
    void* P1     = carve(ND * tsz(nt));     // Ex then Bx
    void* e      = carve(ED * tsz(et));
    void* e_ij   = carve(ED * tsz(jt));
    void* x_new  = P0;

    k_zero<<<(NN + 255) / 256, 256, 0, stream>>>(deg, NN);
    k_zero<<<8, 256, 0, stream>>>((int*)e_stats, 2048);
    k_wprep<<<256, 256, 0, stream>>>(WC, WCf);

    int egrid = (EE + 255) / 256;
    k_count<<<egrid, 256, 0, stream>>>(edst, deg);
    k_scan<<<1, 1024, 0, stream>>>(deg, row_ptr, cursor);
    k_scatter<<<egrid, 256, 0, stream>>>(edst, cursor, perm);

    const int ngemm_grid = (NN + 63) / 64;
    const int edge_grid  = (EE + 63) / 64;
    const int aggr_grid  = (NN + 3) / 4;
    const int upd_grid   = (NN * DD + 255) / 256;

    for (int l = 0; l < LL; l++) {
        const void* xin = (l == 0) ? (const void*)X_n : (const void*)x_buf;
        int xint = (l == 0) ? 0 : xt;

        // phase A: Dx -> P0, Ex -> P1
        k_node_gemm2<<<ngemm_grid, 256, 0, stream>>>(
            xin, xint,
            WD + (size_t)l * DD * DD, WE + (size_t)l * DD * DD,
            bD + l * DD, bE + l * DD, P0, P1, nt);

        int prev = (l > 0) ? (l - 1) : 0;
        k_edge_mfma<<<edge_grid, 256, 0, stream>>>(
            l, (l < 3) ? 1 : 0, (l < 3) ? 1 : 0,
            e, et, e_ij, jt, esrc, edst, eattr, bond,
            WCf + (size_t)l * 16384, bC + l * DD,
            P0, P1, nt,
            e_stats + prev * 256, bn_e_g + prev * DD, bn_e_b + prev * DD,
            e_stats + l * 256);

        // phase B: Ax -> P0, Bx -> P1
        k_node_gemm2<<<ngemm_grid, 256, 0, stream>>>(
            xin, xint,
            WA + (size_t)l * DD * DD, WB + (size_t)l * DD * DD,
            bA + l * DD, bB + l * DD, P0, P1, nt);

        k_aggr<<<aggr_grid, 256, 0, stream>>>(row_ptr, perm, esrc, e_ij, jt, P1, P0, nt, x_new);
        k_xstats<<<256, 256, 0, stream>>>(x_new, nt, x_stats + l * 256);

        void* xo = (l == 3) ? d_out : x_buf;
        int ot = (l == 3) ? 0 : xt;
        k_xupd<<<upd_grid, 256, 0, stream>>>(xin, xint, x_new, nt, x_stats + l * 256,
                                             bn_x_g + l * DD, bn_x_b + l * DD, xo, ot);
    }
}

// Round 9
// 3581.408 us; speedup vs baseline: 1.8941x; 1.0096x over previous
//
#include <hip/hip_runtime.h>
#include <hip/hip_bf16.h>

#define LL 4
#define NN 50000
#define EE 625000
#define DD 128

#define PADA 136   // bf16 A-tile row pitch (elements)
#define PADO 132   // fp32 out-tile row pitch (elements)
// XOR swizzle on OT columns: breaks 4-threads-per-row same-bank aliasing
#define SW(c) ((c) ^ ((((c) >> 5) & 3) << 3))

typedef __hip_bfloat16 bf16;
typedef unsigned char u8;
typedef unsigned short ushort_t;
typedef unsigned int uint_t;
typedef __attribute__((ext_vector_type(8))) short s8v;   // 8 bf16 (4 VGPRs)
typedef __attribute__((ext_vector_type(4))) float f4v;   // 4 fp32 acc

__device__ __forceinline__ float b2f(bf16 v) { return __bfloat162float(v); }
__device__ __forceinline__ ushort_t f2b_bits(float v) {
    bf16 h = __float2bfloat16(v);
    return *reinterpret_cast<ushort_t*>(&h);
}
__device__ __forceinline__ float bits2f(ushort_t u) {
    bf16 h;
    *reinterpret_cast<ushort_t*>(&h) = u;
    return __bfloat162float(h);
}

// ---- manual OCP fp8 e4m3fn codec ----
__device__ __forceinline__ u8 f2e4m3(float x) {
    if (x != x) return 0x7f;
    u8 s = (x < 0.0f) ? 0x80 : 0x00;
    float a = fabsf(x);
    if (a >= 448.0f) return s | 0x7e;
    if (a < 0.0009765625f) return s;
    int e;
    float m = frexpf(a, &e);
    int E = e - 1;
    if (E < -6) {
        int f = (int)rintf(a * 512.0f);
        if (f >= 8) return s | 0x08;
        return s | (u8)f;
    }
    int f = (int)rintf(m * 16.0f);
    if (f == 16) { E++; f = 8; }
    if (E > 8) return s | 0x7e;
    return s | (u8)(((E + 7) << 3) | (f & 7));
}
__device__ __forceinline__ float e4m32f(u8 v) {
    int ex = (v >> 3) & 0xF, man = v & 7;
    float a;
    if (ex == 0) a = (float)man * 0.001953125f;
    else a = ldexpf(1.0f + (float)man * 0.125f, ex - 7);
    return (v & 0x80) ? -a : a;
}

// ---- typed scalar load/store: t=0 fp32, 1 bf16, 2 fp8 ----
__device__ __forceinline__ float loadT(const void* p, size_t i, int t) {
    if (t == 0) return ((const float*)p)[i];
    if (t == 1) return b2f(((const bf16*)p)[i]);
    return e4m32f(((const u8*)p)[i]);
}
__device__ __forceinline__ void storeT(void* p, size_t i, int t, float v) {
    if (t == 0) ((float*)p)[i] = v;
    else if (t == 1) ((bf16*)p)[i] = __float2bfloat16(v);
    else ((u8*)p)[i] = f2e4m3(v);
}

// ---- pair load/store (i 2-aligned) ----
__device__ __forceinline__ void load2(const void* p, size_t i, int t, float* v) {
    if (t == 0) {
        float2 f = *(const float2*)((const float*)p + i);
        v[0] = f.x; v[1] = f.y;
    } else if (t == 1) {
        uint_t u = *(const uint_t*)((const ushort_t*)p + i);
        v[0] = bits2f((ushort_t)(u & 0xffff));
        v[1] = bits2f((ushort_t)(u >> 16));
    } else {
        ushort_t u = *(const ushort_t*)((const u8*)p + i);
        v[0] = e4m32f((u8)(u & 0xff));
        v[1] = e4m32f((u8)(u >> 8));
    }
}
__device__ __forceinline__ void store2(void* p, size_t i, int t, const float* v) {
    if (t == 0) {
        float2 f; f.x = v[0]; f.y = v[1];
        *(float2*)((float*)p + i) = f;
    } else if (t == 1) {
        uint_t u = (uint_t)f2b_bits(v[0]) | ((uint_t)f2b_bits(v[1]) << 16);
        *(uint_t*)((ushort_t*)p + i) = u;
    } else {
        ushort_t u = (ushort_t)(f2e4m3(v[0]) | (f2e4m3(v[1]) << 8));
        *(ushort_t*)((u8*)p + i) = u;
    }
}

// ---- 8-wide vector load/store (i 8-aligned, 16B-aligned base) ----
__device__ __forceinline__ void load8(const void* p, size_t i, int t, float* v) {
    if (t == 1) {
        uint4 u = *(const uint4*)((const ushort_t*)p + i);
        const ushort_t* us = (const ushort_t*)&u;
#pragma unroll
        for (int j = 0; j < 8; j++) v[j] = bits2f(us[j]);
    } else if (t == 2) {
        uint2 u = *(const uint2*)((const u8*)p + i);
        const u8* b = (const u8*)&u;
#pragma unroll
        for (int j = 0; j < 8; j++) v[j] = e4m32f(b[j]);
    } else {
        float4 f1 = *(const float4*)((const float*)p + i);
        float4 f2 = *(const float4*)((const float*)p + i + 4);
        v[0] = f1.x; v[1] = f1.y; v[2] = f1.z; v[3] = f1.w;
        v[4] = f2.x; v[5] = f2.y; v[6] = f2.z; v[7] = f2.w;
    }
}
__device__ __forceinline__ void store8(void* p, size_t i, int t, const float* v) {
    if (t == 1) {
        ushort_t tmp[8];
#pragma unroll
        for (int j = 0; j < 8; j++) tmp[j] = f2b_bits(v[j]);
        *(uint4*)((ushort_t*)p + i) = *(const uint4*)tmp;
    } else if (t == 2) {
        u8 tmp[8];
#pragma unroll
        for (int j = 0; j < 8; j++) tmp[j] = f2e4m3(v[j]);
        *(uint2*)((u8*)p + i) = *(const uint2*)tmp;
    } else {
        float4 f1, f2;
        f1.x = v[0]; f1.y = v[1]; f1.z = v[2]; f1.w = v[3];
        f2.x = v[4]; f2.y = v[5]; f2.z = v[6]; f2.w = v[7];
        *(float4*)((float*)p + i) = f1;
        *(float4*)((float*)p + i + 4) = f2;
    }
}

// gelu(approximate=True) via exact identity 0.5v(1+tanh(u)) = v*sigmoid(2u)
__device__ __forceinline__ float gelu_tanh(float v) {
    const float c2 = 1.5957691216057308f;   // 2*sqrt(2/pi)
    float u = c2 * (v + 0.044715f * v * v * v);
    return v / (1.0f + __expf(-u));
}
__device__ __forceinline__ float sigmoidf_(float x) {
    return 1.0f / (1.0f + __expf(-x));
}

// ---------------- utility ----------------
__global__ __launch_bounds__(256) void k_zero(int* __restrict__ p, int n) {
    int i = blockIdx.x * 256 + threadIdx.x;
    if (i < n) p[i] = 0;
}

// ---------------- CSR build ----------------
__global__ __launch_bounds__(256) void k_count(const int* __restrict__ edst, int* __restrict__ deg) {
    int e = blockIdx.x * 256 + threadIdx.x;
    if (e < EE) atomicAdd(&deg[edst[e]], 1);
}

__global__ __launch_bounds__(1024) void k_scan(const int* __restrict__ deg, int* __restrict__ row_ptr,
                                               int* __restrict__ cursor) {
    __shared__ int temp[1024];
    __shared__ int carry;
    int tid = threadIdx.x;
    if (tid == 0) carry = 0;
    __syncthreads();
    for (int base = 0; base < NN; base += 1024) {
        int i = base + tid;
        int v = (i < NN) ? deg[i] : 0;
        temp[tid] = v;
        __syncthreads();
        for (int off = 1; off < 1024; off <<= 1) {
            int t = (tid >= off) ? temp[tid - off] : 0;
            __syncthreads();
            temp[tid] += t;
            __syncthreads();
        }
        int excl = temp[tid] - v + carry;
        if (i < NN) { row_ptr[i] = excl; cursor[i] = excl; }
        __syncthreads();
        if (tid == 1023) carry += temp[1023];
        __syncthreads();
    }
    if (tid == 0) row_ptr[NN] = carry;
}

__global__ __launch_bounds__(256) void k_scatter(const int* __restrict__ edst, int* __restrict__ cursor,
                                                 int* __restrict__ perm) {
    int e = blockIdx.x * 256 + threadIdx.x;
    if (e < EE) {
        int p = atomicAdd(&cursor[edst[e]], 1);
        perm[p] = e;
    }
}

// ---------------- W prep: WC -> bf16 B-fragment order ----------------
__global__ __launch_bounds__(256) void k_wprep(const float* __restrict__ WC, ushort_t* __restrict__ WCf) {
    int tid = blockIdx.x * 256 + threadIdx.x;
    if (tid >= 4 * 32 * 64 * 8) return;
    int j = tid & 7;
    int l6 = (tid >> 3) & 63;
    int f = (tid >> 9) & 31;
    int layer = tid >> 14;
    int kc = f >> 3, n = f & 7;
    int k = kc * 32 + (l6 >> 4) * 8 + j;
    int col = n * 16 + (l6 & 15);
    WCf[tid] = f2b_bits(WC[(size_t)layer * 16384 + k * 128 + col]);
}

// ---------------- K1: node GEMM, 2 matrices per call ----------------
__global__ __launch_bounds__(256) void k_node_gemm2(
    const void* __restrict__ x, int xt,
    const float* __restrict__ WX, const float* __restrict__ WY,
    const float* __restrict__ bX, const float* __restrict__ bY,
    void* __restrict__ OX, void* __restrict__ OY, int nt) {
    __shared__ float smem[12352];          // w_lds[64][128] + x_lds[64][65]
    float* w_lds = smem;
    float* x_lds = smem + 8192;
    int tid = threadIdx.x, wid = tid >> 6, lane = tid & 63;
    int base = blockIdx.x * 64;
    for (int m = 0; m < 2; m++) {
        const float* W = (m == 0) ? WX : WY;
        const float* bb = (m == 0) ? bX : bY;
        void* O = (m == 0) ? OX : OY;
        float acc[32];
#pragma unroll
        for (int jj = 0; jj < 32; jj++) acc[jj] = bb[wid * 32 + jj];
        for (int h = 0; h < 2; h++) {
            __syncthreads();
            for (int idx = tid; idx < 8192; idx += 256)
                w_lds[idx] = W[(h * 64 + (idx >> 7)) * 128 + (idx & 127)];
            for (int idx = tid; idx < 4096; idx += 256) {
                int r = idx >> 6, kl = idx & 63;
                int n = base + r;
                float xv = 0.0f;
                if (n < NN) xv = loadT(x, (size_t)n * 128 + h * 64 + kl, xt);
                x_lds[r * 65 + kl] = xv;
            }
            __syncthreads();
            const float4* w4 = (const float4*)w_lds;
            for (int kl = 0; kl < 64; kl++) {
                float xk = x_lds[lane * 65 + kl];
#pragma unroll
                for (int j4 = 0; j4 < 8; j4++) {
                    float4 wv = w4[kl * 32 + wid * 8 + j4];
                    acc[j4 * 4 + 0] += xk * wv.x;
                    acc[j4 * 4 + 1] += xk * wv.y;
                    acc[j4 * 4 + 2] += xk * wv.z;
                    acc[j4 * 4 + 3] += xk * wv.w;
                }
            }
        }
        __syncthreads();
#pragma unroll
        for (int jj = 0; jj < 32; jj++) smem[lane * 129 + wid * 32 + jj] = acc[jj];
        __syncthreads();
        for (int idx = tid; idx < 8192; idx += 256) {
            int r = idx >> 7, k = idx & 127;
            if (base + r < NN) storeT(O, (size_t)(base + r) * 128 + k, nt, smem[r * 129 + k]);
        }
    }
}

// ---------------- K2: fused edge pass (MFMA, latency-overlapped) ----------------
// LDS: [A-tile 17408B | WCf 32768B] unioned with [OT 64*PADO*4=33792B]; + bn.
__global__ __launch_bounds__(256, 3) void k_edge_mfma(
    int layer, int write_e, int accum_stats,
    void* __restrict__ e, int et, void* __restrict__ e_ij, int jt,
    const int* __restrict__ esrc, const int* __restrict__ edst,
    const int* __restrict__ eattr, const float* __restrict__ bond,
    const ushort_t* __restrict__ WCfg, const float* __restrict__ bC,
    const void* __restrict__ Dx, const void* __restrict__ Ex, int nt,
    const float* __restrict__ stats_prev,
    const float* __restrict__ gE, const float* __restrict__ bEb,
    float* __restrict__ stats_out) {
    __shared__ __align__(16) char Ub[50176];
    __shared__ float bnS[128], bnH[128];
    ushort_t* eA = (ushort_t*)Ub;                 // [0, 17408)
    ushort_t* Wl = (ushort_t*)(Ub + 17408);       // [17408, 50176)
    float* OT = (float*)Ub;                       // [0, 33792) after MFMA

    int tid = threadIdx.x;
    int lane = tid & 63, wid = tid >> 6;
    int ln15 = lane & 15, quad = lane >> 4;
    size_t base = (size_t)blockIdx.x * 64;
    const float invE = 1.0f / (float)EE;

    int row = tid >> 2;
    int cb = (tid & 3) * 32;
    size_t grow = base + row;
    bool v = grow < (size_t)EE;

    // ---- 1. early: issue Dx/Ex gathers into registers (overlap everything) ----
    int dn = v ? edst[grow] : 0;
    int sn = v ? esrc[grow] : 0;
    float dx[32], ex[32];
    if (v) {
#pragma unroll
        for (int g = 0; g < 4; g++) {
            load8(Dx, (size_t)dn * 128 + cb + g * 8, nt, &dx[g * 8]);
            load8(Ex, (size_t)sn * 128 + cb + g * 8, nt, &ex[g * 8]);
        }
    } else {
#pragma unroll
        for (int j = 0; j < 32; j++) { dx[j] = 0.0f; ex[j] = 0.0f; }
    }

    // ---- 2. cooperative WCf -> LDS (32KB, coalesced) ----
    {
        const uint4* src = (const uint4*)WCfg;
        uint4* dst = (uint4*)Wl;
#pragma unroll
        for (int k = 0; k < 8; k++) dst[tid + k * 256] = src[tid + k * 256];
    }

    // ---- 3. BN scale/shift precompute ----
    if (tid < 128) {
        float m = stats_prev[tid] * invE;
        float var = stats_prev[128 + tid] * invE - m * m;
        float s = gE[tid] * rsqrtf(var + 1e-5f);
        bnS[tid] = s;
        bnH[tid] = bEb[tid] - m * s;
    }
    __syncthreads();

    // ---- 4. stage e-tile (apply prev e-update, write back), bf16 A-tile ----
    {
        int a0 = 0, a1 = 0, a2 = 0;
        if (v && layer == 0) {
            a0 = eattr[grow * 3 + 0];
            a1 = eattr[grow * 3 + 1];
            a2 = eattr[grow * 3 + 2];
        }
#pragma unroll
        for (int g = 0; g < 4; g++) {
            int k0 = cb + g * 8;
            float vals[8];
            if (v) {
                if (layer == 0) {
#pragma unroll
                    for (int j = 0; j < 8; j++) {
                        int k = k0 + j;
                        vals[j] = bond[a0 * 128 + k] + bond[(37 + a1) * 128 + k]
                                + bond[(74 + a2) * 128 + k];
                    }
                } else {
                    float ep[8], hij[8];
                    load8(e, grow * 128 + k0, et, ep);
                    load8(e_ij, grow * 128 + k0, jt, hij);
#pragma unroll
                    for (int j = 0; j < 8; j++) {
                        int k = k0 + j;
                        float y = bnS[k] * hij[j] + bnH[k];
                        vals[j] = ep[j] + gelu_tanh(y);
                    }
                }
                if (write_e) store8(e, grow * 128 + k0, et, vals);
            } else {
#pragma unroll
                for (int j = 0; j < 8; j++) vals[j] = 0.0f;
            }
            ushort_t tmp[8];
#pragma unroll
            for (int j = 0; j < 8; j++) tmp[j] = f2b_bits(vals[j]);
            *(uint4*)&eA[row * PADA + k0] = *(const uint4*)tmp;
        }
    }
    __syncthreads();

    // ---- 5. MFMA: A from LDS tile, B from LDS WCf ----
    f4v acc[8];
#pragma unroll
    for (int n = 0; n < 8; n++) acc[n] = (f4v)(0.0f);
    {
        const ushort_t* arow = &eA[(wid * 16 + ln15) * PADA + quad * 8];
#pragma unroll
        for (int kc = 0; kc < 4; kc++) {
            s8v a = *(const s8v*)(arow + kc * 32);
#pragma unroll
            for (int n = 0; n < 8; n++) {
                s8v b = *(const s8v*)(Wl + ((kc * 8 + n) * 64 + lane) * 8);
                acc[n] = __builtin_amdgcn_mfma_f32_16x16x32_bf16(a, b, acc[n], 0, 0, 0);
            }
        }
    }
    __syncthreads();   // A-tile & WCf dead; OT live

    // ---- 6. write Ce + bC into OT (C-layout, swizzled cols) ----
    {
        float bcv[8];
#pragma unroll
        for (int n = 0; n < 8; n++) bcv[n] = bC[n * 16 + ln15];
#pragma unroll
        for (int rr = 0; rr < 4; rr++) {
            int lrow = wid * 16 + quad * 4 + rr;
            bool lv = (base + lrow) < (size_t)EE;
#pragma unroll
            for (int n = 0; n < 8; n++) {
                int col = n * 16 + ln15;
                OT[lrow * PADO + SW(col)] = lv ? (acc[n][rr] + bcv[n]) : 0.0f;
            }
        }
    }
    __syncthreads();

    // ---- 7. combine: Ce(row) + dx + ex -> e_ij; optional stats write-back ----
    {
        int swb = ((cb >> 5) & 3) << 3;
        float vals[32];
#pragma unroll
        for (int j = 0; j < 32; j++)
            vals[j] = OT[row * PADO + cb + (j ^ swb)] + dx[j] + ex[j];
        if (v) {
#pragma unroll
            for (int g = 0; g < 4; g++)
                store8(e_ij, grow * 128 + cb + g * 8, jt, &vals[g * 8]);
        }
        if (accum_stats) {
#pragma unroll
            for (int j = 0; j < 32; j++)
                OT[row * PADO + cb + (j ^ swb)] = v ? vals[j] : 0.0f;
        }
    }

    // ---- 8. BN-e stats (fp32, swizzled column reads) ----
    if (accum_stats) {
        __syncthreads();
        int c = tid & 127, hh = tid >> 7;
        int sc = SW(c);
        float s = 0.0f, q = 0.0f;
        for (int r = 0; r < 64; r++) {
            float x = OT[r * PADO + sc];
            s += x;
            q += x * x;
        }
        if (hh == 0) atomicAdd(&stats_out[c], s);
        else         atomicAdd(&stats_out[128 + c], q);
    }
}

// ---------------- K3: CSR aggregation (wave per node, column pairs) ----------------
__global__ __launch_bounds__(256) void k_aggr(
    const int* __restrict__ row_ptr, const int* __restrict__ perm,
    const int* __restrict__ esrc, const void* __restrict__ e_ij, int jt,
    const void* __restrict__ Bx, const void* __restrict__ Ax, int nt,
    void* __restrict__ x_new) {
    int tid = threadIdx.x, wid = tid >> 6, lane = tid & 63;
    int n = blockIdx.x * 4 + wid;
    if (n >= NN) return;
    int s0 = row_ptr[n], s1 = row_ptr[n + 1];
    int c0 = 2 * lane;
    float num0 = 0.0f, num1 = 0.0f, den0 = 0.0f, den1 = 0.0f;
    int i = s0;
    int eid_n = 0, src_n = 0;
    if (i < s1) { eid_n = perm[i]; src_n = esrc[eid_n]; }
    while (i < s1) {
        int eid = eid_n, src = src_n;
        int ip = i + 1;
        if (ip < s1) { eid_n = perm[ip]; src_n = esrc[eid_n]; }
        float h[2], b[2];
        load2(e_ij, (size_t)eid * 128 + c0, jt, h);
        load2(Bx, (size_t)src * 128 + c0, nt, b);
        float g0 = sigmoidf_(h[0]);
        float g1 = sigmoidf_(h[1]);
        num0 += g0 * b[0];
        num1 += g1 * b[1];
        den0 += g0;
        den1 += g1;
        i = ip;
    }
    float a[2];
    load2(Ax, (size_t)n * 128 + c0, nt, a);
    float o[2] = { a[0] + num0 / (den0 + 1e-6f), a[1] + num1 / (den1 + 1e-6f) };
    store2(x_new, (size_t)n * 128 + c0, nt, o);
}

// ---------------- K4: per-channel stats of x_new ----------------
__global__ __launch_bounds__(256) void k_xstats(const void* __restrict__ x_new, int nt,
                                                float* __restrict__ stats) {
    int tid = threadIdx.x;
    int c = tid & 127, hh = tid >> 7;
    float s = 0.0f, q = 0.0f;
    for (int r = blockIdx.x * 2 + hh; r < NN; r += (int)gridDim.x * 2) {
        float v = loadT(x_new, (size_t)r * 128 + c, nt);
        s += v;
        q += v * v;
    }
    atomicAdd(&stats[c], s);
    atomicAdd(&stats[128 + c], q);
}

// ---------------- K5: x update ----------------
__global__ __launch_bounds__(256) void k_xupd(
    const void* __restrict__ xin, int xt,
    const void* __restrict__ x_new, int nt,
    const float* __restrict__ stats, const float* __restrict__ g,
    const float* __restrict__ bb, void* __restrict__ xout, int ot) {
    __shared__ float sc[128], sh[128];
    int tid = threadIdx.x;
    if (tid < 128) {
        const float invN = 1.0f / (float)NN;
        float m = stats[tid] * invN;
        float var = stats[128 + tid] * invN - m * m;
        float s = g[tid] * rsqrtf(var + 1e-5f);
        sc[tid] = s;
        sh[tid] = bb[tid] - m * s;
    }
    __syncthreads();
    int idx = blockIdx.x * 256 + tid;
    if (idx >= NN * 128) return;
    int c = idx & 127;
    float y = sc[c] * loadT(x_new, idx, nt) + sh[c];
    float xi = loadT(xin, idx, xt);
    storeT(xout, idx, ot, xi + gelu_tanh(y));
}

extern "C" void kernel_launch(void* const* d_in, const int* in_sizes, int n_in,
                              void* d_out, int out_size, void* d_ws, size_t ws_size,
                              hipStream_t stream) {
    const float* X_n  = (const float*)d_in[0];
    const int*  eidx  = (const int*)d_in[2];
    const int*  eattr = (const int*)d_in[3];
    const float* bond = (const float*)d_in[4];
    const float* WA = (const float*)d_in[5];  const float* bA = (const float*)d_in[6];
    const float* WB = (const float*)d_in[7];  const float* bB = (const float*)d_in[8];
    const float* WC = (const float*)d_in[9];  const float* bC = (const float*)d_in[10];
    const float* WD = (const float*)d_in[11]; const float* bD = (const float*)d_in[12];
    const float* WE = (const float*)d_in[13]; const float* bE = (const float*)d_in[14];
    const float* bn_x_g = (const float*)d_in[15];
    const float* bn_x_b = (const float*)d_in[16];
    const float* bn_e_g = (const float*)d_in[17];
    const float* bn_e_b = (const float*)d_in[18];

    const int* esrc = eidx;
    const int* edst = eidx + EE;

    // ---- precision ladder ----
    auto tsz = [](int t) -> size_t { return t == 0 ? 4 : (t == 1 ? 2 : 1); };
    int cfgs[7][4] = {
        {1, 1, 0, 0},   // ~400 MB
        {1, 1, 1, 0},   // ~374 MB
        {1, 2, 0, 0},   // ~320 MB
        {1, 2, 1, 0},   // ~294 MB
        {2, 2, 0, 0},   // ~240 MB
        {2, 2, 1, 0},   // ~214 MB
        {2, 2, 1, 1},   // ~202 MB
    };
    const size_t ND = (size_t)NN * DD, ED = (size_t)EE * DD;
    int chosen = -1;
    for (int c = 0; c < 7; c++) {
        size_t need = ED * (tsz(cfgs[c][0]) + tsz(cfgs[c][1]))
                    + ND * (2 * tsz(cfgs[c][2]) + tsz(cfgs[c][3]))
                    + 2048 * 4
                    + ((size_t)NN * 3 + 1 + EE) * 4
                    + 4 * 16384 * 2
                    + 20 * 256;
        if (ws_size >= need) { chosen = c; break; }
    }
    if (chosen < 0) return;
    int et = cfgs[chosen][0], jt = cfgs[chosen][1], nt = cfgs[chosen][2], xt = cfgs[chosen][3];

    size_t off = 0;
    auto carve = [&](size_t bytes) -> void* {
        void* p = (char*)d_ws + off;
        off += (bytes + 255) & ~(size_t)255;
        return p;
    };
    float* e_stats = (float*)carve(1024 * 4);
    float* x_stats = (float*)carve(1024 * 4);
    int* deg     = (int*)carve((size_t)NN * 4);
    int* row_ptr = (int*)carve(((size_t)NN + 1) * 4);
    int* cursor  = (int*)carve((size_t)NN * 4);
    int* perm    = (int*)carve((size_t)EE * 4);
    ushort_t* WCf = (ushort_t*)carve(4 * 16384 * 2);
    void* x_buf  = carve(ND * tsz(xt));
    void* P0     = carve(ND * tsz(nt));     // Dx then Ax; x_new aliases P0
    void* P1     = carve(ND * tsz(nt));     // Ex then Bx
    void* e      = carve(ED * tsz(et));
    void* e_ij   = carve(ED * tsz(jt));
    void* x_new  = P0;

    k_zero<<<(NN + 255) / 256, 256, 0, stream>>>(deg, NN);
    k_zero<<<8, 256, 0, stream>>>((int*)e_stats, 2048);
    k_wprep<<<256, 256, 0, stream>>>(WC, WCf);

    int egrid = (EE + 255) / 256;
    k_count<<<egrid, 256, 0, stream>>>(edst, deg);
    k_scan<<<1, 1024, 0, stream>>>(deg, row_ptr, cursor);
    k_scatter<<<egrid, 256, 0, stream>>>(edst, cursor, perm);

    const int ngemm_grid = (NN + 63) / 64;
    const int edge_grid  = (EE + 63) / 64;
    const int aggr_grid  = (NN + 3) / 4;
    const int upd_grid   = (NN * DD + 255) / 256;

    for (int l = 0; l < LL; l++) {
        const void* xin = (l == 0) ? (const void*)X_n : (const void*)x_buf;
        int xint = (l == 0) ? 0 : xt;

        // phase A: Dx -> P0, Ex -> P1
        k_node_gemm2<<<ngemm_grid, 256, 0, stream>>>(
            xin, xint,
            WD + (size_t)l * DD * DD, WE + (size_t)l * DD * DD,
            bD + l * DD, bE + l * DD, P0, P1, nt);

        int prev = (l > 0) ? (l - 1) : 0;
        k_edge_mfma<<<edge_grid, 256, 0, stream>>>(
            l, (l < 3) ? 1 : 0, (l < 3) ? 1 : 0,
            e, et, e_ij, jt, esrc, edst, eattr, bond,
            WCf + (size_t)l * 16384, bC + l * DD,
            P0, P1, nt,
            e_stats + prev * 256, bn_e_g + prev * DD, bn_e_b + prev * DD,
            e_stats + l * 256);

        // phase B: Ax -> P0, Bx -> P1
        k_node_gemm2<<<ngemm_grid, 256, 0, stream>>>(
            xin, xint,
            WA + (size_t)l * DD * DD, WB + (size_t)l * DD * DD,
            bA + l * DD, bB + l * DD, P0, P1, nt);

        k_aggr<<<aggr_grid, 256, 0, stream>>>(row_ptr, perm, esrc, e_ij, jt, P1, P0, nt, x_new);
        k_xstats<<<256, 256, 0, stream>>>(x_new, nt, x_stats + l * 256);

        void* xo = (l == 3) ? d_out : x_buf;
        int ot = (l == 3) ? 0 : xt;
        k_xupd<<<upd_grid, 256, 0, stream>>>(xin, xint, x_new, nt, x_stats + l * 256,
                                             bn_x_g + l * DD, bn_x_b + l * DD, xo, ot);
    }
}